// Round 9
// baseline (218.566 us; speedup 1.0000x reference)
//
#include <hip/hip_runtime.h>

// LabelGenerator: masks [32,1,768,768] f32 in {0,1}
//  out0 = 35x35 box mean (SAME, zero pad)      -> f32 [32,768,768]
//  out1 = pfm: mask?1 : (31x31 dilation?0 : 2) -> f32 values 0/1/2
// R9: two-pass via tiny byte intermediate (18.9 MB, LLC-resident).
//  K1 (hmap): per row, ballot-pack 768 cols -> funnel-shift windows ->
//     packed byte per col: h35(6b) | mask<<6 | or31<<7. No halo, no barriers
//     (wave-synchronous). 75.5 MB read + 18.9 MB write.
//  K2 (vslide): vertical sliding sums straight from the global h-map:
//     per 4 cols/row: 3 predicated u32 loads (LLC) + 2-deep ring registers
//     + SWAR updates + 2 coalesced float4 stores. No LDS. 151 MB write-bound.
// Dilation on a 0/1 mask == (31x31 box sum >= 1).

#define BATCH 32
#define HH 768
#define WW 768
#define NPIX (HH * WW)

// ---------------- K1: horizontal h-map ----------------
constexpr int K1_RPB = 16;   // rows per block (4 waves x 4 rows)

__global__ __launch_bounds__(256)
void hmap_kernel(const float* __restrict__ in, unsigned int* __restrict__ hmg) {
    __shared__ unsigned long long sb[4][14];
    const int lane = threadIdx.x & 63;
    const int wv   = threadIdx.x >> 6;
    const int b    = blockIdx.y;
    const int r0   = blockIdx.x * K1_RPB;
    const float* __restrict__ src = in + (size_t)b * NPIX;
    unsigned int* __restrict__ dst = hmg + (size_t)b * (NPIX / 4);
    const unsigned long long M35 = (1ull << 35) - 1;
    auto bit = [](unsigned long long w, int k) -> unsigned {
        return (unsigned)((w >> k) & 1ull);
    };

    for (int r = r0 + wv; r < r0 + K1_RPB; r += 4) {
        const float* rp = src + (size_t)r * WW;
        unsigned long long bb[12];
        #pragma unroll
        for (int j = 0; j < 12; ++j) bb[j] = __ballot(rp[64 * j + lane] > 0.5f);
        if (lane == 0) {
            sb[wv][0] = 0ull;
            #pragma unroll
            for (int j = 0; j < 12; ++j) sb[wv][j + 1] = bb[j];
            sb[wv][13] = 0ull;
        }
        __builtin_amdgcn_wave_barrier();
        #pragma unroll
        for (int it = 0; it < 3; ++it) {
            const int gi = it * 64 + lane;        // 4-col group 0..191
            const int s  = 4 * gi - 17;
            const int q  = (s >> 6) + 1;          // arith shift handles s<0
            const int sh = s & 63;                // odd -> never 0
            const unsigned long long w =
                (sb[wv][q] >> sh) | (sb[wv][q + 1] << (64 - sh));
            const unsigned h0 = (unsigned)__popcll(w & M35);
            const unsigned h1 = h0 + bit(w, 35) - bit(w, 0);
            const unsigned h2 = h1 + bit(w, 36) - bit(w, 1);
            const unsigned h3 = h2 + bit(w, 37) - bit(w, 2);
            unsigned long long sm = w | (w >> 1);          // 16-smear
            sm |= sm >> 2; sm |= sm >> 4; sm |= sm >> 8;
            const unsigned o4 = (unsigned)(((sm >> 2) | (sm >> 17)) & 0xFull);
            const unsigned m4 = (unsigned)((w >> 17) & 0xFull);
            const unsigned x = h0 | (h1 << 8) | (h2 << 16) | (h3 << 24)
                             | ((m4 & 1u) << 6)  | ((m4 & 2u) << 13)
                             | ((m4 & 4u) << 20) | ((m4 & 8u) << 27)
                             | ((o4 & 1u) << 7)  | ((o4 & 2u) << 14)
                             | ((o4 & 4u) << 21) | ((o4 & 8u) << 28);
            dst[(size_t)r * 192 + gi] = x;
        }
        __builtin_amdgcn_wave_barrier();
    }
}

// ---------------- K2: vertical slide + outputs ----------------
constexpr int TYO = 48;     // rows per block (4 groups x 12)
constexpr int RPG = 12;

__global__ __launch_bounds__(768)
void vslide_kernel(const unsigned int* __restrict__ hmg, float* __restrict__ out) {
    const int tid = threadIdx.x;
    const int g   = tid / 192;          // 0..3
    const int ct  = tid - g * 192;      // 0..191 (4 cols each)
    const int y0  = blockIdx.x * TYO;
    const int b   = blockIdx.y;
    const int yb  = y0 + RPG * g;
    const unsigned int* __restrict__ hb = hmg + (size_t)b * (NPIX / 4) + ct;
    auto ld = [&](int r) -> unsigned {
        return ((unsigned)r < (unsigned)HH) ? hb[(size_t)r * 192] : 0u;
    };
    const unsigned M6 = 0x003F003Fu;    // h fields of bytes (0,2)/(1,3)
    const unsigned M1 = 0x01010101u;    // or-flag per byte

    unsigned vA = 0, vB = 0, c31 = 0;
    unsigned ring_a[2], ring_s[2];
    #pragma unroll
    for (int k = 0; k < 35; ++k) {
        const unsigned x = ld(yb - 17 + k);
        vA += x & M6;
        vB += (x >> 8) & M6;
        if (k >= 2 && k <= 32) c31 += (x >> 7) & M1;
        if (k == 0)  ring_s[0] = x;     // row yb-17: sub35 at i=0
        if (k == 1)  ring_s[1] = x;     // row yb-16: sub35 at i=1
        if (k == 33) ring_a[0] = x;     // row yb+16: add31 at i=0
        if (k == 34) ring_a[1] = x;     // row yb+17: add31 at i=1
    }

    float* orow = out + (size_t)b * NPIX + (size_t)yb * WW + 4 * ct;
    float* prow = orow + (size_t)BATCH * NPIX;

    for (int i = 0; i < RPG; ++i) {
        const int y = yb + i;
        const unsigned xc = hb[(size_t)y * 192];   // center row (always valid)

        float4 r4, p4;
        r4.x = (float)(vA & 0xFFFFu) * (1.0f / 1225.0f);
        r4.y = (float)(vB & 0xFFFFu) * (1.0f / 1225.0f);
        r4.z = (float)(vA >> 16)     * (1.0f / 1225.0f);
        r4.w = (float)(vB >> 16)     * (1.0f / 1225.0f);
        p4.x = ((xc >> 6) & 1u)  ? 1.0f : ((c31 & 0xFFu)         ? 0.0f : 2.0f);
        p4.y = ((xc >> 14) & 1u) ? 1.0f : (((c31 >> 8) & 0xFFu)  ? 0.0f : 2.0f);
        p4.z = ((xc >> 22) & 1u) ? 1.0f : (((c31 >> 16) & 0xFFu) ? 0.0f : 2.0f);
        p4.w = ((xc >> 30) & 1u) ? 1.0f : ((c31 >> 24)           ? 0.0f : 2.0f);

        *(float4*)orow = r4;
        *(float4*)prow = p4;
        orow += WW; prow += WW;

        if (i < RPG - 1) {
            const unsigned xa = ld(y + 18);        // add35 now, add31 at i+2
            const unsigned xs = ld(y - 15);        // sub31 now, sub35 at i+2
            const unsigned a31 = ring_a[i & 1];  ring_a[i & 1] = xa;
            const unsigned s35 = ring_s[i & 1];  ring_s[i & 1] = xs;
            // per-field: 0 <= v35 <= 1225 < 2^16, 0 <= c31 <= 31 < 2^8 -> SWAR-safe
            vA  = (vA + (xa & M6)) - (s35 & M6);
            vB  = (vB + ((xa >> 8) & M6)) - ((s35 >> 8) & M6);
            c31 = (c31 + ((a31 >> 7) & M1)) - ((xs >> 7) & M1);
        }
    }
}

// ---------------- Fallback: R7 fused single kernel (passing) ----------------
constexpr int F_HALO = 17;
constexpr int F_ROWS = TYO + 2 * F_HALO;   // 82
constexpr int F_SSEG = 14;

__global__ __launch_bounds__(768)
void label_gen_fused(const float* __restrict__ in, float* __restrict__ out) {
    __shared__ unsigned long long sbits[F_ROWS][F_SSEG];
    __shared__ unsigned int hm[F_ROWS][192];

    const int tid  = threadIdx.x;
    const int lane = tid & 63;
    const int wv   = tid >> 6;
    const int y0   = blockIdx.x * TYO;
    const int b    = blockIdx.y;
    const float* __restrict__ src = in + (size_t)b * NPIX;

    for (int lr = wv; lr < F_ROWS; lr += 12) {
        const int r = y0 - F_HALO + lr;
        unsigned long long bb[12];
        if ((unsigned)r < (unsigned)HH) {
            const float* rp = src + (size_t)r * WW;
            #pragma unroll
            for (int j = 0; j < 12; ++j) bb[j] = __ballot(rp[64 * j + lane] > 0.5f);
        } else {
            #pragma unroll
            for (int j = 0; j < 12; ++j) bb[j] = 0ull;
        }
        if (lane == 0) {
            sbits[lr][0] = 0ull;
            #pragma unroll
            for (int j = 0; j < 12; ++j) sbits[lr][j + 1] = bb[j];
            sbits[lr][13] = 0ull;
        }
    }
    __syncthreads();

    {
        const int r0 = tid / 192;
        const int ct = tid - r0 * 192;
        const int s  = 4 * ct - 17;
        const int q  = (s >> 6) + 1;
        const int sh = s & 63;
        const unsigned long long M35 = (1ull << 35) - 1;
        for (int lr = r0; lr < F_ROWS; lr += 4) {
            const unsigned long long w =
                (sbits[lr][q] >> sh) | (sbits[lr][q + 1] << (64 - sh));
            const unsigned h0 = (unsigned)__popcll(w & M35);
            const unsigned h1 = h0 + (unsigned)((w >> 35) & 1) - (unsigned)(w & 1);
            const unsigned h2 = h1 + (unsigned)((w >> 36) & 1) - (unsigned)((w >> 1) & 1);
            const unsigned h3 = h2 + (unsigned)((w >> 37) & 1) - (unsigned)((w >> 2) & 1);
            unsigned long long sm = w | (w >> 1);
            sm |= sm >> 2; sm |= sm >> 4; sm |= sm >> 8;
            const unsigned o4 = (unsigned)(((sm >> 2) | (sm >> 17)) & 0xFull);
            const unsigned m4 = (unsigned)((w >> 17) & 0xFull);
            hm[lr][ct] = h0 | (h1 << 8) | (h2 << 16) | (h3 << 24)
                       | ((m4 & 1u) << 6)  | ((m4 & 2u) << 13)
                       | ((m4 & 4u) << 20) | ((m4 & 8u) << 27)
                       | ((o4 & 1u) << 7)  | ((o4 & 2u) << 14)
                       | ((o4 & 4u) << 21) | ((o4 & 8u) << 28);
        }
    }
    __syncthreads();

    const int g   = tid / 192;
    const int ct  = tid - g * 192;
    const int yb  = y0 + RPG * g;
    const int lr0 = RPG * g;
    const unsigned M6 = 0x003F003Fu;
    const unsigned M1 = 0x01010101u;

    unsigned vA = 0, vB = 0, c31 = 0;
    unsigned ring_e[2], ring_l[2];
    #pragma unroll
    for (int k = 0; k < 35; ++k) {
        const unsigned x = hm[lr0 + k][ct];
        vA += x & M6;
        vB += (x >> 8) & M6;
        if (k >= 2 && k <= 32) c31 += (x >> 7) & M1;
        if (k == 0)  ring_l[0] = x;
        if (k == 1)  ring_l[1] = x;
        if (k == 33) ring_e[0] = x;
        if (k == 34) ring_e[1] = x;
    }

    float* orow = out + (size_t)b * NPIX + (size_t)yb * WW + 4 * ct;
    float* prow = orow + (size_t)BATCH * NPIX;

    for (int i = 0; i < RPG; ++i) {
        const int lr = lr0 + F_HALO + i;
        const unsigned xc = hm[lr][ct];
        float4 r4, p4;
        r4.x = (float)(vA & 0xFFFFu) * (1.0f / 1225.0f);
        r4.y = (float)(vB & 0xFFFFu) * (1.0f / 1225.0f);
        r4.z = (float)(vA >> 16)     * (1.0f / 1225.0f);
        r4.w = (float)(vB >> 16)     * (1.0f / 1225.0f);
        p4.x = ((xc >> 6) & 1u)  ? 1.0f : ((c31 & 0xFFu)         ? 0.0f : 2.0f);
        p4.y = ((xc >> 14) & 1u) ? 1.0f : (((c31 >> 8) & 0xFFu)  ? 0.0f : 2.0f);
        p4.z = ((xc >> 22) & 1u) ? 1.0f : (((c31 >> 16) & 0xFFu) ? 0.0f : 2.0f);
        p4.w = ((xc >> 30) & 1u) ? 1.0f : ((c31 >> 24)           ? 0.0f : 2.0f);
        *(float4*)orow = r4;
        *(float4*)prow = p4;
        orow += WW; prow += WW;
        if (i < RPG - 1) {
            const unsigned xe   = hm[lr + 18][ct];
            const unsigned xl31 = hm[lr0 + 2 + i][ct];
            const unsigned xe31 = ring_e[i & 1];
            const unsigned xl   = ring_l[i & 1];
            ring_e[i & 1] = xe;
            ring_l[i & 1] = xl31;
            vA  = (vA + (xe & M6)) - (xl & M6);
            vB  = (vB + ((xe >> 8) & M6)) - ((xl >> 8) & M6);
            c31 = (c31 + ((xe31 >> 7) & M1)) - ((xl31 >> 7) & M1);
        }
    }
}

extern "C" void kernel_launch(void* const* d_in, const int* in_sizes, int n_in,
                              void* d_out, int out_size, void* d_ws, size_t ws_size,
                              hipStream_t stream) {
    const float* masks = (const float*)d_in[0];
    float* out = (float*)d_out;
    const size_t need = (size_t)BATCH * NPIX;   // 18.9 MB byte h-map
    if (ws_size >= need) {
        unsigned int* hmg = (unsigned int*)d_ws;
        dim3 g1(HH / K1_RPB, BATCH);    // 48 x 32
        hmap_kernel<<<g1, 256, 0, stream>>>(masks, hmg);
        dim3 g2(HH / TYO, BATCH);       // 16 x 32
        vslide_kernel<<<g2, 768, 0, stream>>>(hmg, out);
    } else {
        dim3 grid(HH / TYO, BATCH);
        label_gen_fused<<<grid, 768, 0, stream>>>(masks, out);
    }
}

// Round 10
// 211.668 us; speedup vs baseline: 1.0326x; 1.0326x over previous
//
#include <hip/hip_runtime.h>

// LabelGenerator: masks [32,1,768,768] f32 in {0,1}
//  out0 = 35x35 box mean (SAME, zero pad)      -> f32 [32,768,768]
//  out1 = pfm: mask?1 : (31x31 dilation?0 : 2) -> f32 values 0/1/2
// R10 = R7 fused three-phase kernel (best: 211.8) + NON-TEMPORAL output
// stores: the 151 MB output stream bypasses L2/LLC so the input + h-map
// working set stays cache-resident (harness poison-fills flush 720 MiB
// through the 256 MB LLC every iteration; cached write-allocate stores
// were churning what's left).
// Dilation on a 0/1 mask == (31x31 box sum >= 1).

#define BATCH 32
#define HH 768
#define WW 768
#define NPIX (HH * WW)

constexpr int TYO  = 48;               // output rows per block
constexpr int HALO = 17;               // 35//2
constexpr int ROWS = TYO + 2 * HALO;   // 82 staged rows
constexpr int NSEG = 12;               // 768/64 u64 segments per row
constexpr int SSEG = NSEG + 2;         // +2 zero-pad segments
constexpr int NT   = 768;              // threads per block (12 waves)
constexpr int NG   = 4;                // row groups
constexpr int RPG  = TYO / NG;         // 12 output rows per group
constexpr int CT   = 192;              // col-threads per group (x4 cols)

typedef float v4f __attribute__((ext_vector_type(4)));

__global__ __launch_bounds__(NT)
void label_gen_fused(const float* __restrict__ in, float* __restrict__ out) {
    __shared__ unsigned long long sbits[ROWS][SSEG];   // 9184 B
    __shared__ unsigned int hm[ROWS][CT];              // 62976 B packed bytes

    const int tid  = threadIdx.x;
    const int lane = tid & 63;
    const int wv   = tid >> 6;          // 0..11
    const int y0   = blockIdx.x * TYO;
    const int b    = blockIdx.y;
    const float* __restrict__ src = in + (size_t)b * NPIX;

    // ---- Phase A: global f32 -> LDS bit rows (ballot pack) ----
    for (int lr = wv; lr < ROWS; lr += NT / 64) {
        const int r = y0 - HALO + lr;
        unsigned long long bb[NSEG];
        if ((unsigned)r < (unsigned)HH) {          // wave-uniform branch
            const float* rp = src + (size_t)r * WW;
            #pragma unroll
            for (int j = 0; j < NSEG; ++j)
                bb[j] = __ballot(rp[64 * j + lane] > 0.5f);
        } else {
            #pragma unroll
            for (int j = 0; j < NSEG; ++j) bb[j] = 0ull;
        }
        if (lane == 0) {
            sbits[lr][0] = 0ull;
            #pragma unroll
            for (int j = 0; j < NSEG; ++j) sbits[lr][j + 1] = bb[j];
            sbits[lr][SSEG - 1] = 0ull;
        }
    }
    __syncthreads();

    // ---- Phase H: per-row horizontal values, each row evaluated once ----
    {
        const int r0 = tid / CT;            // 0..3
        const int ct = tid - r0 * CT;       // 0..191
        const int c0 = 4 * ct;
        const int s  = c0 - HALO;
        const int q  = (s >> 6) + 1;        // padded u64 index (arith shift)
        const int sh = s & 63;              // odd -> never 0
        const unsigned long long M35 = (1ull << 35) - 1;
        for (int lr = r0; lr < ROWS; lr += NG) {
            // win bit j = mask col c0-17+j
            const unsigned long long w =
                (sbits[lr][q] >> sh) | (sbits[lr][q + 1] << (64 - sh));
            const int h0 = (int)__popcll(w & M35);
            const int h1 = h0 + (int)((w >> 35) & 1) - (int)(w & 1);
            const int h2 = h1 + (int)((w >> 36) & 1) - (int)((w >> 1) & 1);
            const int h3 = h2 + (int)((w >> 37) & 1) - (int)((w >> 2) & 1);
            // 16-smear: sm bit k = OR of w bits k..k+15
            unsigned long long sm = w | (w >> 1);
            sm |= sm >> 2; sm |= sm >> 4; sm |= sm >> 8;
            // or31 for col c0+j = OR of w bits (j+2)..(j+32) = sm[j+2]|sm[j+17]
            const unsigned int o4 = (unsigned int)(((sm >> 2) | (sm >> 17)) & 0xFull);
            const unsigned int m4 = (unsigned int)((w >> 17) & 0xFull);
            const unsigned int mb =
                (((m4 & 1u) | ((m4 & 2u) << 7) | ((m4 & 4u) << 14) | ((m4 & 8u) << 21)) << 6);
            const unsigned int ob =
                (((o4 & 1u) | ((o4 & 2u) << 7) | ((o4 & 4u) << 14) | ((o4 & 8u) << 21)) << 7);
            hm[lr][ct] = (unsigned)h0 | ((unsigned)h1 << 8) | ((unsigned)h2 << 16)
                       | ((unsigned)h3 << 24) | mb | ob;
        }
    }
    __syncthreads();

    // ---- Phase B: vertical SWAR sliding sums over packed bytes ----
    const int g   = tid / CT;           // 0..3
    const int ct  = tid - g * CT;       // 0..191
    const int c0  = 4 * ct;
    const int yb  = y0 + RPG * g;       // group's first output row
    const int lr0 = RPG * g;            // LDS row of image row yb-17

    const unsigned int M6 = 0x003F003Fu;   // 6-bit h fields of bytes (0,2)/(1,3)
    const unsigned int M1 = 0x01010101u;   // or-flag per byte

    unsigned int vA = 0, vB = 0;   // 2x16-bit fields: cols (0,2) and (1,3)
    unsigned int c31 = 0;          // 4x8-bit or-flag counts per col
    unsigned int ring_e[2], ring_l[2];
    #pragma unroll
    for (int k = 0; k < 35; ++k) {
        const unsigned int x = hm[lr0 + k][ct];
        vA += x & M6;
        vB += (x >> 8) & M6;
        if (k >= 2 && k <= 32) c31 += (x >> 7) & M1;
        if (k == 0)  ring_l[0] = x;    // row lr0+0 (l35 at i=0)
        if (k == 1)  ring_l[1] = x;    // row lr0+1 (l35 at i=1)
        if (k == 33) ring_e[0] = x;    // row lr0+33 (e31 at i=0)
        if (k == 34) ring_e[1] = x;    // row lr0+34 (e31 at i=1)
    }

    float* orow = out + (size_t)b * NPIX + (size_t)yb * WW + c0;
    float* prow = orow + (size_t)BATCH * NPIX;

    for (int i = 0; i < RPG; ++i) {
        const int lr = lr0 + HALO + i;         // LDS row of output row yb+i
        const unsigned int xc = hm[lr][ct];    // center row (mask bits)

        v4f r4, p4;
        r4.x = (float)(vA & 0xFFFFu) * (1.0f / 1225.0f);
        r4.y = (float)(vB & 0xFFFFu) * (1.0f / 1225.0f);
        r4.z = (float)(vA >> 16)     * (1.0f / 1225.0f);
        r4.w = (float)(vB >> 16)     * (1.0f / 1225.0f);
        p4.x = ((xc >> 6) & 1u)  ? 1.0f : ((c31 & 0xFFu)         ? 0.0f : 2.0f);
        p4.y = ((xc >> 14) & 1u) ? 1.0f : (((c31 >> 8) & 0xFFu)  ? 0.0f : 2.0f);
        p4.z = ((xc >> 22) & 1u) ? 1.0f : (((c31 >> 16) & 0xFFu) ? 0.0f : 2.0f);
        p4.w = ((xc >> 30) & 1u) ? 1.0f : ((c31 >> 24)           ? 0.0f : 2.0f);

        __builtin_nontemporal_store(r4, (v4f*)orow);   // bypass L2/LLC
        __builtin_nontemporal_store(p4, (v4f*)prow);
        orow += WW; prow += WW;

        if (i < RPG - 1) {
            const unsigned int xe   = hm[lr + 18][ct];      // e35 row lr0+35+i
            const unsigned int xl31 = hm[lr0 + 2 + i][ct];  // l31 row lr0+2+i
            const unsigned int xe31 = ring_e[i & 1];        // e31 row lr0+33+i
            const unsigned int xl   = ring_l[i & 1];        // l35 row lr0+i
            ring_e[i & 1] = xe;                             // reused at i+2
            ring_l[i & 1] = xl31;                           // reused at i+2
            // per-field: 0 <= value <= 1225+35 < 2^16 (and <=32 < 2^8) -> SWAR-safe
            vA  = (vA + (xe & M6)) - (xl & M6);
            vB  = (vB + ((xe >> 8) & M6)) - ((xl >> 8) & M6);
            c31 = (c31 + ((xe31 >> 7) & M1)) - ((xl31 >> 7) & M1);
        }
    }
}

extern "C" void kernel_launch(void* const* d_in, const int* in_sizes, int n_in,
                              void* d_out, int out_size, void* d_ws, size_t ws_size,
                              hipStream_t stream) {
    const float* masks = (const float*)d_in[0];
    float* out = (float*)d_out;
    dim3 grid(HH / TYO, BATCH);    // 16 x 32 = 512 blocks, 2 per CU
    label_gen_fused<<<grid, NT, 0, stream>>>(masks, out);
}